// Round 12
// baseline (42.184 us; speedup 1.0000x reference)
//
#include <hip/hip_runtime.h>
#include <math.h>

#define S 256
#define H 1024
#define NPAIR 32640  // S*(S-1)/2

// ---- workspace layout (float indices) ----
#define WS_T     0          // [8 kc][256 s][1024 c] score GEMM partials (8 MB)
#define WS_HP    2097152    // [8 kc][3 p][256 s][20 t] hw partials (480 KB)
#define WS_A     2220032    // [256]
#define WS_HW0   2220804    // [256*20]
#define WS_HW1   2225924    // [256*20]
#define WS_HW2   2231044    // [256*20]
#define WS_LW    2241304    // [257*20] indexed by L=j-i+1
#define WS_LOSSP 2246444    // [255]

__device__ __forceinline__ float tanh_fast(float x) {
    const float xc = fminf(fmaxf(x, -15.f), 15.f);
    const float ex = __expf(2.f * xc);
    return (ex - 1.f) / (ex + 1.f);
}

// ============ K1: score partials (8-row tiles, halved w1 L2 redundancy) + hw partials ============
// b<256:  score. kc=b>>5 (128-k chunk), rg=b&31 (rows rg*8..+7). Thread: 4 cols.
//         Per k: 1 coalesced float4 w-load + 2 broadcast ds_read_b128 + 32 FMA.
// b>=256: hw partials (rg=hb&15, kc=hb>>4) — verified path, unchanged.
__global__ __launch_bounds__(256) void K1(const float* __restrict__ hidden,
                                          const float* __restrict__ w1,
                                          const float* __restrict__ fcw,
                                          float* __restrict__ ws) {
    const int tid = threadIdx.x;
    const int b = blockIdx.x;

    if (b < 256) {
        __shared__ __align__(16) float shH[128][8];
        const int kc = b >> 5, rg = b & 31;
        #pragma unroll
        for (int e = 0; e < 4; e++) {
            const int li = e * 256 + tid;
            const int kk = li & 127, r = li >> 7;     // r 0..7
            shH[kk][r] = hidden[(rg * 8 + r) * H + kc * 128 + kk];
        }
        __syncthreads();
        float4 acc[8];
        #pragma unroll
        for (int r = 0; r < 8; r++) acc[r] = make_float4(0.f, 0.f, 0.f, 0.f);
        const float* wp = w1 + (size_t)(kc * 128) * H + tid * 4;
        #pragma unroll 4
        for (int k = 0; k < 128; k++) {
            const float4 wv = *(const float4*)&wp[(size_t)k * H];
            const float4 hA = *(const float4*)&shH[k][0];
            const float4 hB = *(const float4*)&shH[k][4];
            acc[0].x = fmaf(hA.x, wv.x, acc[0].x); acc[0].y = fmaf(hA.x, wv.y, acc[0].y);
            acc[0].z = fmaf(hA.x, wv.z, acc[0].z); acc[0].w = fmaf(hA.x, wv.w, acc[0].w);
            acc[1].x = fmaf(hA.y, wv.x, acc[1].x); acc[1].y = fmaf(hA.y, wv.y, acc[1].y);
            acc[1].z = fmaf(hA.y, wv.z, acc[1].z); acc[1].w = fmaf(hA.y, wv.w, acc[1].w);
            acc[2].x = fmaf(hA.z, wv.x, acc[2].x); acc[2].y = fmaf(hA.z, wv.y, acc[2].y);
            acc[2].z = fmaf(hA.z, wv.z, acc[2].z); acc[2].w = fmaf(hA.z, wv.w, acc[2].w);
            acc[3].x = fmaf(hA.w, wv.x, acc[3].x); acc[3].y = fmaf(hA.w, wv.y, acc[3].y);
            acc[3].z = fmaf(hA.w, wv.z, acc[3].z); acc[3].w = fmaf(hA.w, wv.w, acc[3].w);
            acc[4].x = fmaf(hB.x, wv.x, acc[4].x); acc[4].y = fmaf(hB.x, wv.y, acc[4].y);
            acc[4].z = fmaf(hB.x, wv.z, acc[4].z); acc[4].w = fmaf(hB.x, wv.w, acc[4].w);
            acc[5].x = fmaf(hB.y, wv.x, acc[5].x); acc[5].y = fmaf(hB.y, wv.y, acc[5].y);
            acc[5].z = fmaf(hB.y, wv.z, acc[5].z); acc[5].w = fmaf(hB.y, wv.w, acc[5].w);
            acc[6].x = fmaf(hB.z, wv.x, acc[6].x); acc[6].y = fmaf(hB.z, wv.y, acc[6].y);
            acc[6].z = fmaf(hB.z, wv.z, acc[6].z); acc[6].w = fmaf(hB.z, wv.w, acc[6].w);
            acc[7].x = fmaf(hB.w, wv.x, acc[7].x); acc[7].y = fmaf(hB.w, wv.y, acc[7].y);
            acc[7].z = fmaf(hB.w, wv.z, acc[7].z); acc[7].w = fmaf(hB.w, wv.w, acc[7].w);
        }
        float* op = ws + WS_T + (size_t)kc * (S * H) + (size_t)(rg * 8) * H + tid * 4;
        #pragma unroll
        for (int r = 0; r < 8; r++)
            *(float4*)&op[(size_t)r * H] = acc[r];
    } else {
        __shared__ __align__(16) float shHT[128][20];
        const int hb = b - 256;
        const int rg = hb & 15, kc = hb >> 4;
        {
            const int c = tid & 127, rr = tid >> 7;
            #pragma unroll
            for (int e = 0; e < 8; e++) {
                const int r = e * 2 + rr;
                shHT[c][r] = hidden[(rg * 16 + r) * H + kc * 128 + c];
            }
        }
        __syncthreads();
        if (tid < 240) {
            const int t = tid % 20, g = tid / 20;   // g 0..11
            const int p = g >> 2, rsub = g & 3;
            const float* fw = fcw + (size_t)(p * H + kc * 128) * 20 + t;
            float a0 = 0.f, a1 = 0.f, a2 = 0.f, a3 = 0.f;
            #pragma unroll 8
            for (int k = 0; k < 128; k++) {
                const float w = fw[k * 20];
                const float4 h4 = *(const float4*)&shHT[k][rsub * 4];
                a0 = fmaf(h4.x, w, a0);
                a1 = fmaf(h4.y, w, a1);
                a2 = fmaf(h4.z, w, a2);
                a3 = fmaf(h4.w, w, a3);
            }
            float* hpo = ws + WS_HP + ((size_t)(kc * 3 + p) * 256 + rg * 16 + rsub * 4) * 20 + t;
            hpo[0] = a0; hpo[20] = a1; hpo[40] = a2; hpo[60] = a3;
        }
    }
}

// ============ K2: row reduce + tanh + w2 dot + hw reduce; block 0 also lw ============
__global__ __launch_bounds__(256) void K2(const float* __restrict__ b1,
                                          const float* __restrict__ w2,
                                          const float* __restrict__ lenemb,
                                          const float* __restrict__ fcw,
                                          float* __restrict__ ws) {
    const int b = blockIdx.x, tid = threadIdx.x;
    __shared__ float sred[256];
    {
        const int c = tid * 4;
        float4 sum = make_float4(0.f, 0.f, 0.f, 0.f);
        #pragma unroll
        for (int kcz = 0; kcz < 8; kcz++) {
            const float4 tv = *(const float4*)&ws[WS_T + (size_t)kcz * (S * H) + (size_t)b * H + c];
            sum.x += tv.x; sum.y += tv.y; sum.z += tv.z; sum.w += tv.w;
        }
        const float4 b4 = *(const float4*)&b1[c];
        const float4 w4 = *(const float4*)&w2[c];
        sred[tid] = tanh_fast(sum.x + b4.x) * w4.x
                  + tanh_fast(sum.y + b4.y) * w4.y
                  + tanh_fast(sum.z + b4.z) * w4.z
                  + tanh_fast(sum.w + b4.w) * w4.w;
    }
    __syncthreads();
    for (int off = 128; off > 0; off >>= 1) {
        if (tid < off) sred[tid] += sred[tid + off];
        __syncthreads();
    }
    if (tid == 0) ws[WS_A + b] = sred[0];

    if (tid < 60) {
        const int t = tid % 20, p = tid / 20;
        float s = 0.f;
        #pragma unroll
        for (int kc = 0; kc < 8; kc++)
            s += ws[WS_HP + ((size_t)(kc * 3 + p) * 256 + b) * 20 + t];
        const int base = (p == 0) ? WS_HW0 : (p == 1) ? WS_HW1 : WS_HW2;
        ws[base + b * 20 + t] = s;
    }

    if (b == 0) {   // lw table: L=2..256
        for (int item = tid; item < 5100; item += 256) {
            const int L2i = item / 20, t = item % 20;
            float v = 0.f;
            #pragma unroll
            for (int d = 0; d < 10; d++)
                v = fmaf(lenemb[(L2i + 2) * 10 + d], fcw[(3072 + d) * 20 + t], v);
            ws[WS_LW + (L2i + 2) * 20 + t] = v;
        }
    }
}

// ============ K3: pair rows with replicated scan prologue (R11-verified) ============
__global__ __launch_bounds__(256) void K3(const int* __restrict__ target,
                                          const float* __restrict__ b2,
                                          const float* __restrict__ fcb,
                                          float* __restrict__ out,
                                          float* __restrict__ ws) {
    const int i = blockIdx.x;
    const int j = threadIdx.x;
    const int s = j;
    __shared__ float shf[256], she[256];
    __shared__ int shi[256], shtg[256];
    __shared__ float shw0[5120];
    __shared__ float shpw[5120];
    __shared__ float soff[4][20];
    __shared__ float sPwi[20], shw1i[20], sfcb[20];
    __shared__ float sred[256];

    for (int idx = s; idx < 5120; idx += 256) shw0[idx] = ws[WS_HW0 + idx];
    shtg[s] = target[s];
    const float a = ws[WS_A + s] + b2[0];
    sred[s] = a;
    __syncthreads();
    for (int off = 128; off > 0; off >>= 1) {
        if (s < off) sred[s] = fmaxf(sred[s], sred[s + off]);
        __syncthreads();
    }
    const float mx = sred[0];
    __syncthreads();
    const float ev = __expf(a - mx);
    she[s] = ev;
    shf[s] = ev;
    const int chg = (s == 0) ? 1 : (shtg[s] != shtg[s - 1]);
    shi[s] = chg;
    __syncthreads();
    for (int off = 1; off < 256; off <<= 1) {
        const float fv = (s >= off) ? shf[s - off] : 0.f;
        const int   iv = (s >= off) ? shi[s - off] : 0;
        __syncthreads();
        shf[s] += fv;     // -> ZC[s+1]
        shi[s] += iv;     // -> runid[s]
        __syncthreads();
    }
    if (s < 80) {
        const int t = s % 20, seg = s / 20;
        const int base = seg * 64;
        float pw = 0.f;
        for (int k = 0; k < 64; k++) {
            pw = fmaf(she[base + k], shw0[(base + k) * 20 + t], pw);
            shpw[(base + k) * 20 + t] = pw;
        }
    }
    __syncthreads();
    if (s < 20) {
        const float T0 = shpw[63 * 20 + s], T1 = shpw[127 * 20 + s], T2 = shpw[191 * 20 + s];
        soff[0][s] = 0.f; soff[1][s] = T0; soff[2][s] = T0 + T1; soff[3][s] = T0 + T1 + T2;
        sPwi[s]  = (i == 0) ? 0.f : shpw[(i - 1) * 20 + s] + soff[(i - 1) >> 6][s];
        shw1i[s] = ws[WS_HW1 + i * 20 + s];
        sfcb[s]  = fcb[s];
    }
    __syncthreads();

    float lossacc = 0.f;
    if (j > i) {
        const float ZCi  = (i == 0) ? 0.f : shf[i - 1];
        const float invz = 1.f / (shf[j] - ZCi);
        const int L = j - i + 1;
        const int sti = (i == 0) ? 1 : (shtg[i] != shtg[i - 1]);
        const int enj = (j == 255) ? 1 : (shtg[j] != shtg[j + 1]);
        const int lbl = (shi[i] == shi[j] && sti && enj) ? shtg[j] : 0;

        const float4* pj4 = (const float4*)&shpw[j * 20];
        const float4* so4 = (const float4*)&soff[j >> 6][0];
        const float4* pi4 = (const float4*)sPwi;
        const float4* h14 = (const float4*)shw1i;
        const float4* h24 = (const float4*)&ws[WS_HW2 + j * 20];
        const float4* lw4 = (const float4*)&ws[WS_LW + L * 20];
        const float4* fb4 = (const float4*)sfcb;
        const int p = i * (511 - i) / 2 + (j - i - 1);
        float4* op4 = (float4*)(out + (size_t)p * 20);

        float lg[20];
        float mxl = -1e30f, chosen = 0.f;
        #pragma unroll
        for (int q = 0; q < 5; q++) {
            const float4 pj = pj4[q], so = so4[q], pi = pi4[q];
            const float4 h1 = h14[q], h2 = h24[q];
            const float4 lw = lw4[q], fb = fb4[q];
            float4 r;
            r.x = (pj.x + so.x - pi.x) * invz + h1.x + h2.x + lw.x + fb.x;
            r.y = (pj.y + so.y - pi.y) * invz + h1.y + h2.y + lw.y + fb.y;
            r.z = (pj.z + so.z - pi.z) * invz + h1.z + h2.z + lw.z + fb.z;
            r.w = (pj.w + so.w - pi.w) * invz + h1.w + h2.w + lw.w + fb.w;
            op4[q] = r;
            lg[q * 4 + 0] = r.x; lg[q * 4 + 1] = r.y;
            lg[q * 4 + 2] = r.z; lg[q * 4 + 3] = r.w;
            mxl = fmaxf(mxl, fmaxf(fmaxf(r.x, r.y), fmaxf(r.z, r.w)));
            chosen = (q * 4 + 0 == lbl) ? r.x : chosen;
            chosen = (q * 4 + 1 == lbl) ? r.y : chosen;
            chosen = (q * 4 + 2 == lbl) ? r.z : chosen;
            chosen = (q * 4 + 3 == lbl) ? r.w : chosen;
        }
        float se = 0.f;
        #pragma unroll
        for (int t = 0; t < 20; t++) se += __expf(lg[t] - mxl);
        lossacc = -(chosen - mxl - __logf(se));
    }
    sred[j] = lossacc;
    __syncthreads();
    for (int off = 128; off > 0; off >>= 1) {
        if (j < off) sred[j] += sred[j + off];
        __syncthreads();
    }
    if (j == 0) ws[WS_LOSSP + i] = sred[0];
}

// ============ K4: final loss reduce over 255 partials ============
__global__ __launch_bounds__(256) void K4(float* __restrict__ out,
                                          float* __restrict__ ws) {
    __shared__ float sh[256];
    const int t = threadIdx.x;
    sh[t] = (t < 255) ? ws[WS_LOSSP + t] : 0.f;
    __syncthreads();
    for (int off = 128; off > 0; off >>= 1) {
        if (t < off) sh[t] += sh[t + off];
        __syncthreads();
    }
    if (t == 0) out[(size_t)NPAIR * 20] = sh[0] / (float)NPAIR;
}

extern "C" void kernel_launch(void* const* d_in, const int* in_sizes, int n_in,
                              void* d_out, int out_size, void* d_ws, size_t ws_size,
                              hipStream_t stream) {
    (void)in_sizes; (void)n_in; (void)out_size; (void)ws_size;
    const float* hidden = (const float*)d_in[0];
    const int*   target = (const int*)d_in[1];
    const float* w1     = (const float*)d_in[2];
    const float* b1     = (const float*)d_in[3];
    const float* w2     = (const float*)d_in[4];
    const float* b2     = (const float*)d_in[5];
    const float* lenemb = (const float*)d_in[6];
    const float* fcw    = (const float*)d_in[7];
    const float* fcb    = (const float*)d_in[8];
    float* out = (float*)d_out;
    float* ws  = (float*)d_ws;

    K1<<<384, 256, 0, stream>>>(hidden, w1, fcw, ws);
    K2<<<256, 256, 0, stream>>>(b1, w2, lenemb, fcw, ws);
    K3<<<255, 256, 0, stream>>>(target, b2, fcb, out, ws);
    K4<<<1, 256, 0, stream>>>(out, ws);
}

// Round 13
// 37.037 us; speedup vs baseline: 1.1390x; 1.1390x over previous
//
#include <hip/hip_runtime.h>
#include <math.h>

#define S 256
#define H 1024
#define NPAIR 32640  // S*(S-1)/2

// ---- workspace layout (float indices) ----
#define WS_T     0          // [8 kc][256 s][1024 c] score GEMM partials (8 MB)
#define WS_HP    2097152    // [8 kc][3 p][256 s][20 t] hw partials (480 KB)
#define WS_A     2220032    // [256]
#define WS_HW0   2220804    // [256*20]
#define WS_HW1   2225924    // [256*20]
#define WS_HW2   2231044    // [256*20]
#define WS_LW    2241304    // [257*20] indexed by L=j-i+1
#define WS_LOSSP 2246444    // [255]

__device__ __forceinline__ float tanh_fast(float x) {
    const float xc = fminf(fmaxf(x, -15.f), 15.f);
    const float ex = __expf(2.f * xc);
    return (ex - 1.f) / (ex + 1.f);
}

// ============ K1: score partials + hw partials (R11-verified: 37.2us total) ============
// b<512:  score. kc=b>>6 (128-k chunk), rg=b&63 (4 rows). Thread: 4 cols.
//         Per k: 1 coalesced float4 w-load + 1 broadcast ds_read_b128 + 16 FMA.
// b>=512: hw partials (rg=hb&15, kc=hb>>4).
__global__ __launch_bounds__(256) void K1(const float* __restrict__ hidden,
                                          const float* __restrict__ w1,
                                          const float* __restrict__ fcw,
                                          float* __restrict__ ws) {
    const int tid = threadIdx.x;
    const int b = blockIdx.x;

    if (b < 512) {
        __shared__ __align__(16) float shH[128][4];
        const int kc = b >> 6, rg = b & 63;
        #pragma unroll
        for (int e = 0; e < 2; e++) {
            const int li = e * 256 + tid;
            const int kk = li & 127, r = li >> 7;
            shH[kk][r] = hidden[(rg * 4 + r) * H + kc * 128 + kk];
        }
        __syncthreads();
        float4 a0 = make_float4(0.f, 0.f, 0.f, 0.f), a1 = a0, a2 = a0, a3 = a0;
        const float* wp = w1 + (size_t)(kc * 128) * H + tid * 4;
        #pragma unroll 8
        for (int k = 0; k < 128; k++) {
            const float4 wv = *(const float4*)&wp[(size_t)k * H];
            const float4 h4 = *(const float4*)&shH[k][0];
            a0.x = fmaf(h4.x, wv.x, a0.x); a0.y = fmaf(h4.x, wv.y, a0.y);
            a0.z = fmaf(h4.x, wv.z, a0.z); a0.w = fmaf(h4.x, wv.w, a0.w);
            a1.x = fmaf(h4.y, wv.x, a1.x); a1.y = fmaf(h4.y, wv.y, a1.y);
            a1.z = fmaf(h4.y, wv.z, a1.z); a1.w = fmaf(h4.y, wv.w, a1.w);
            a2.x = fmaf(h4.z, wv.x, a2.x); a2.y = fmaf(h4.z, wv.y, a2.y);
            a2.z = fmaf(h4.z, wv.z, a2.z); a2.w = fmaf(h4.z, wv.w, a2.w);
            a3.x = fmaf(h4.w, wv.x, a3.x); a3.y = fmaf(h4.w, wv.y, a3.y);
            a3.z = fmaf(h4.w, wv.z, a3.z); a3.w = fmaf(h4.w, wv.w, a3.w);
        }
        float* op = ws + WS_T + (size_t)kc * (S * H) + (size_t)(rg * 4) * H + tid * 4;
        *(float4*)&op[0]     = a0;
        *(float4*)&op[H]     = a1;
        *(float4*)&op[2 * H] = a2;
        *(float4*)&op[3 * H] = a3;
    } else {
        __shared__ __align__(16) float shHT[128][20];
        const int hb = b - 512;
        const int rg = hb & 15, kc = hb >> 4;
        {
            const int c = tid & 127, rr = tid >> 7;
            #pragma unroll
            for (int e = 0; e < 8; e++) {
                const int r = e * 2 + rr;
                shHT[c][r] = hidden[(rg * 16 + r) * H + kc * 128 + c];
            }
        }
        __syncthreads();
        if (tid < 240) {
            const int t = tid % 20, g = tid / 20;   // g 0..11
            const int p = g >> 2, rsub = g & 3;
            const float* fw = fcw + (size_t)(p * H + kc * 128) * 20 + t;
            float a0 = 0.f, a1 = 0.f, a2 = 0.f, a3 = 0.f;
            #pragma unroll 8
            for (int k = 0; k < 128; k++) {
                const float w = fw[k * 20];
                const float4 h4 = *(const float4*)&shHT[k][rsub * 4];
                a0 = fmaf(h4.x, w, a0);
                a1 = fmaf(h4.y, w, a1);
                a2 = fmaf(h4.z, w, a2);
                a3 = fmaf(h4.w, w, a3);
            }
            float* hpo = ws + WS_HP + ((size_t)(kc * 3 + p) * 256 + rg * 16 + rsub * 4) * 20 + t;
            hpo[0] = a0; hpo[20] = a1; hpo[40] = a2; hpo[60] = a3;
        }
    }
}

// ============ K2: row reduce + tanh + w2 dot + hw reduce; block 0 also lw ============
__global__ __launch_bounds__(256) void K2(const float* __restrict__ b1,
                                          const float* __restrict__ w2,
                                          const float* __restrict__ lenemb,
                                          const float* __restrict__ fcw,
                                          float* __restrict__ ws) {
    const int b = blockIdx.x, tid = threadIdx.x;
    __shared__ float sred[256];
    {
        const int c = tid * 4;
        float4 sum = make_float4(0.f, 0.f, 0.f, 0.f);
        #pragma unroll
        for (int kcz = 0; kcz < 8; kcz++) {
            const float4 tv = *(const float4*)&ws[WS_T + (size_t)kcz * (S * H) + (size_t)b * H + c];
            sum.x += tv.x; sum.y += tv.y; sum.z += tv.z; sum.w += tv.w;
        }
        const float4 b4 = *(const float4*)&b1[c];
        const float4 w4 = *(const float4*)&w2[c];
        sred[tid] = tanh_fast(sum.x + b4.x) * w4.x
                  + tanh_fast(sum.y + b4.y) * w4.y
                  + tanh_fast(sum.z + b4.z) * w4.z
                  + tanh_fast(sum.w + b4.w) * w4.w;
    }
    __syncthreads();
    for (int off = 128; off > 0; off >>= 1) {
        if (tid < off) sred[tid] += sred[tid + off];
        __syncthreads();
    }
    if (tid == 0) ws[WS_A + b] = sred[0];

    if (tid < 60) {
        const int t = tid % 20, p = tid / 20;
        float s = 0.f;
        #pragma unroll
        for (int kc = 0; kc < 8; kc++)
            s += ws[WS_HP + ((size_t)(kc * 3 + p) * 256 + b) * 20 + t];
        const int base = (p == 0) ? WS_HW0 : (p == 1) ? WS_HW1 : WS_HW2;
        ws[base + b * 20 + t] = s;
    }

    if (b == 0) {   // lw table: L=2..256
        for (int item = tid; item < 5100; item += 256) {
            const int L2i = item / 20, t = item % 20;
            float v = 0.f;
            #pragma unroll
            for (int d = 0; d < 10; d++)
                v = fmaf(lenemb[(L2i + 2) * 10 + d], fcw[(3072 + d) * 20 + t], v);
            ws[WS_LW + (L2i + 2) * 20 + t] = v;
        }
    }
}

// ============ K3: pair rows with replicated scan prologue (R11-verified) ============
__global__ __launch_bounds__(256) void K3(const int* __restrict__ target,
                                          const float* __restrict__ b2,
                                          const float* __restrict__ fcb,
                                          float* __restrict__ out,
                                          float* __restrict__ ws) {
    const int i = blockIdx.x;
    const int j = threadIdx.x;
    const int s = j;
    __shared__ float shf[256], she[256];
    __shared__ int shi[256], shtg[256];
    __shared__ float shw0[5120];
    __shared__ float shpw[5120];
    __shared__ float soff[4][20];
    __shared__ float sPwi[20], shw1i[20], sfcb[20];
    __shared__ float sred[256];

    for (int idx = s; idx < 5120; idx += 256) shw0[idx] = ws[WS_HW0 + idx];
    shtg[s] = target[s];
    const float a = ws[WS_A + s] + b2[0];
    sred[s] = a;
    __syncthreads();
    for (int off = 128; off > 0; off >>= 1) {
        if (s < off) sred[s] = fmaxf(sred[s], sred[s + off]);
        __syncthreads();
    }
    const float mx = sred[0];
    __syncthreads();
    const float ev = __expf(a - mx);
    she[s] = ev;
    shf[s] = ev;
    const int chg = (s == 0) ? 1 : (shtg[s] != shtg[s - 1]);
    shi[s] = chg;
    __syncthreads();
    for (int off = 1; off < 256; off <<= 1) {
        const float fv = (s >= off) ? shf[s - off] : 0.f;
        const int   iv = (s >= off) ? shi[s - off] : 0;
        __syncthreads();
        shf[s] += fv;     // -> ZC[s+1]
        shi[s] += iv;     // -> runid[s]
        __syncthreads();
    }
    if (s < 80) {
        const int t = s % 20, seg = s / 20;
        const int base = seg * 64;
        float pw = 0.f;
        for (int k = 0; k < 64; k++) {
            pw = fmaf(she[base + k], shw0[(base + k) * 20 + t], pw);
            shpw[(base + k) * 20 + t] = pw;
        }
    }
    __syncthreads();
    if (s < 20) {
        const float T0 = shpw[63 * 20 + s], T1 = shpw[127 * 20 + s], T2 = shpw[191 * 20 + s];
        soff[0][s] = 0.f; soff[1][s] = T0; soff[2][s] = T0 + T1; soff[3][s] = T0 + T1 + T2;
        sPwi[s]  = (i == 0) ? 0.f : shpw[(i - 1) * 20 + s] + soff[(i - 1) >> 6][s];
        shw1i[s] = ws[WS_HW1 + i * 20 + s];
        sfcb[s]  = fcb[s];
    }
    __syncthreads();

    float lossacc = 0.f;
    if (j > i) {
        const float ZCi  = (i == 0) ? 0.f : shf[i - 1];
        const float invz = 1.f / (shf[j] - ZCi);
        const int L = j - i + 1;
        const int sti = (i == 0) ? 1 : (shtg[i] != shtg[i - 1]);
        const int enj = (j == 255) ? 1 : (shtg[j] != shtg[j + 1]);
        const int lbl = (shi[i] == shi[j] && sti && enj) ? shtg[j] : 0;

        const float4* pj4 = (const float4*)&shpw[j * 20];
        const float4* so4 = (const float4*)&soff[j >> 6][0];
        const float4* pi4 = (const float4*)sPwi;
        const float4* h14 = (const float4*)shw1i;
        const float4* h24 = (const float4*)&ws[WS_HW2 + j * 20];
        const float4* lw4 = (const float4*)&ws[WS_LW + L * 20];
        const float4* fb4 = (const float4*)sfcb;
        const int p = i * (511 - i) / 2 + (j - i - 1);
        float4* op4 = (float4*)(out + (size_t)p * 20);

        float lg[20];
        float mxl = -1e30f, chosen = 0.f;
        #pragma unroll
        for (int q = 0; q < 5; q++) {
            const float4 pj = pj4[q], so = so4[q], pi = pi4[q];
            const float4 h1 = h14[q], h2 = h24[q];
            const float4 lw = lw4[q], fb = fb4[q];
            float4 r;
            r.x = (pj.x + so.x - pi.x) * invz + h1.x + h2.x + lw.x + fb.x;
            r.y = (pj.y + so.y - pi.y) * invz + h1.y + h2.y + lw.y + fb.y;
            r.z = (pj.z + so.z - pi.z) * invz + h1.z + h2.z + lw.z + fb.z;
            r.w = (pj.w + so.w - pi.w) * invz + h1.w + h2.w + lw.w + fb.w;
            op4[q] = r;
            lg[q * 4 + 0] = r.x; lg[q * 4 + 1] = r.y;
            lg[q * 4 + 2] = r.z; lg[q * 4 + 3] = r.w;
            mxl = fmaxf(mxl, fmaxf(fmaxf(r.x, r.y), fmaxf(r.z, r.w)));
            chosen = (q * 4 + 0 == lbl) ? r.x : chosen;
            chosen = (q * 4 + 1 == lbl) ? r.y : chosen;
            chosen = (q * 4 + 2 == lbl) ? r.z : chosen;
            chosen = (q * 4 + 3 == lbl) ? r.w : chosen;
        }
        float se = 0.f;
        #pragma unroll
        for (int t = 0; t < 20; t++) se += __expf(lg[t] - mxl);
        lossacc = -(chosen - mxl - __logf(se));
    }
    sred[j] = lossacc;
    __syncthreads();
    for (int off = 128; off > 0; off >>= 1) {
        if (j < off) sred[j] += sred[j + off];
        __syncthreads();
    }
    if (j == 0) ws[WS_LOSSP + i] = sred[0];
}

// ============ K4: final loss reduce over 255 partials ============
__global__ __launch_bounds__(256) void K4(float* __restrict__ out,
                                          float* __restrict__ ws) {
    __shared__ float sh[256];
    const int t = threadIdx.x;
    sh[t] = (t < 255) ? ws[WS_LOSSP + t] : 0.f;
    __syncthreads();
    for (int off = 128; off > 0; off >>= 1) {
        if (t < off) sh[t] += sh[t + off];
        __syncthreads();
    }
    if (t == 0) out[(size_t)NPAIR * 20] = sh[0] / (float)NPAIR;
}

extern "C" void kernel_launch(void* const* d_in, const int* in_sizes, int n_in,
                              void* d_out, int out_size, void* d_ws, size_t ws_size,
                              hipStream_t stream) {
    (void)in_sizes; (void)n_in; (void)out_size; (void)ws_size;
    const float* hidden = (const float*)d_in[0];
    const int*   target = (const int*)d_in[1];
    const float* w1     = (const float*)d_in[2];
    const float* b1     = (const float*)d_in[3];
    const float* w2     = (const float*)d_in[4];
    const float* b2     = (const float*)d_in[5];
    const float* lenemb = (const float*)d_in[6];
    const float* fcw    = (const float*)d_in[7];
    const float* fcb    = (const float*)d_in[8];
    float* out = (float*)d_out;
    float* ws  = (float*)d_ws;

    K1<<<640, 256, 0, stream>>>(hidden, w1, fcw, ws);
    K2<<<256, 256, 0, stream>>>(b1, w2, lenemb, fcw, ws);
    K3<<<255, 256, 0, stream>>>(target, b2, fcb, out, ws);
    K4<<<1, 256, 0, stream>>>(out, ws);
}